// Round 1
// 111.959 us; speedup vs baseline: 1.0522x; 1.0522x over previous
//
#include <hip/hip_runtime.h>
#include <math.h>

namespace {
constexpr int N  = 4096;
constexpr int F  = 32;
constexpr int U  = 32;
constexpr int NH = 2;

__device__ __forceinline__ float leaky(float x) {
    return x >= 0.f ? x : 0.2f * x;
}

// X = H @ W per head (real & imag), plus attention-logit vectors.
// Interleaved layouts for single-segment gathers in attn:
//   Xp[(n*NH + h)*U + u] = (xr, xi)   -> one neighbor = 64 consecutive float2 (512 B)
//   Sp[n*NH + h] = (sr, si)           -> one neighbor = 2 consecutive float2 (16 B)
//   Np[n*NH + h] = (nr, ni)
__global__ __launch_bounds__(256) void proj_kernel(
    const float* __restrict__ Hr, const float* __restrict__ Hi,
    const float* __restrict__ W,  const float* __restrict__ a1,
    const float* __restrict__ a2,
    float2* __restrict__ Xp, float2* __restrict__ Sp, float2* __restrict__ Np)
{
    __shared__ float sW[NH * F * U];   // 8 KB
    __shared__ float sH[2][8][F];      // 2 KB
    const int t = threadIdx.x;
    {   // vectorized W stage: 2048 floats = 512 float4, 2 per thread
        const float4* __restrict__ W4 = (const float4*)W;
        float4* __restrict__ sW4 = (float4*)sW;
        sW4[t]       = W4[t];
        sW4[t + 256] = W4[t + 256];
    }
    const int row0 = blockIdx.x * 8;
    {
        const int r = t >> 5, f = t & 31;   // 256 threads = 8 rows x 32 f
        sH[0][r][f] = Hr[(row0 + r) * F + f];
        sH[1][r][f] = Hi[(row0 + r) * F + f];
    }
    __syncthreads();

    const int r = t >> 5, u = t & 31;
    const int n = row0 + r;
    float xr[NH] = {0.f, 0.f}, xi[NH] = {0.f, 0.f};
    #pragma unroll
    for (int h = 0; h < NH; ++h) {
        #pragma unroll
        for (int f = 0; f < F; ++f) {
            const float w = sW[h * F * U + f * U + u];   // u-consecutive: conflict-free
            xr[h] += sH[0][r][f] * w;                    // broadcast read
            xi[h] += sH[1][r][f] * w;
        }
    }
    #pragma unroll
    for (int h = 0; h < NH; ++h)
        Xp[((size_t)n * NH + h) * U + u] = make_float2(xr[h], xi[h]);

    #pragma unroll
    for (int h = 0; h < NH; ++h) {
        const float av1 = a1[h * U + u], av2 = a2[h * U + u];
        float vsr = xr[h] * av1, vnr = xr[h] * av2;
        float vsi = xi[h] * av1, vni = xi[h] * av2;
        #pragma unroll
        for (int m = 16; m; m >>= 1) {   // width-32 butterfly over u
            vsr += __shfl_xor(vsr, m, 32);
            vnr += __shfl_xor(vnr, m, 32);
            vsi += __shfl_xor(vsi, m, 32);
            vni += __shfl_xor(vni, m, 32);
        }
        if (u == 0) {
            Sp[n * NH + h] = make_float2(vsr, vsi);
            Np[n * NH + h] = make_float2(vnr, vni);
        }
    }
}

__device__ __forceinline__ void nb_acc(bool valid, float2 sv, float2 nnc, float2 xc,
                                       float& l1, float& l2,
                                       float& a1r, float& a1i,
                                       float& a2r, float& a2i)
{
    float w1 = __expf(leaky(sv.x + nnc.x));   // alpha1 numerator
    float w2 = __expf(leaky(sv.y + nnc.y));   // alpha2 numerator
    w1 = valid ? w1 : 0.f;                    // padded tail contributes exactly 0
    w2 = valid ? w2 : 0.f;
    l1 += w1; l2 += w2;
    a1r += w1 * xc.x; a1i += w1 * xc.y;
    a2r += w2 * xc.x; a2i += w2 * xc.y;
}

// One WAVE per row.
// Phase A: full 16 KB A-row into 64 VGPRs (16 dwordx4 in flight -> one exposed
//   HBM latency), order-free ballot-prefix compaction of nonzero column
//   indices into a per-wave LDS list, padded to a multiple of 4 with the
//   (always-valid) self index.
// Phase B: 4-wide neighbor-group software pipeline:
//   - int4 index read (1 LDS op per 4 neighbors), prefetched ONE GROUP AHEAD
//     so the LDS->global dependent chain is broken;
//   - all 8 gathers (4x Np broadcast 16 B + 4x Xp contiguous 512 B) of group
//     g+1 issued before consuming group g  -> 8+ loads in flight vs 2 before.
//   Plain-exp softmax (logits bounded, masked entries contribute exactly 0).
// Lane layout: h = lane>>5, u = lane&31; interleaved Xp makes each neighbor's
//   gather one contiguous 64-float2 segment (offset nj*64 + lane).
__global__ __launch_bounds__(256, 4) void attn_kernel(
    const float* __restrict__ A,
    const float2* __restrict__ Xp, const float2* __restrict__ Sp,
    const float2* __restrict__ Np,
    float* __restrict__ out)
{
    __shared__ int s_idx[4][136];   // per-wave neighbor index list (+pad room)

    const int wv   = threadIdx.x >> 6;
    const int lane = threadIdx.x & 63;
    const int i    = blockIdx.x * 4 + wv;
    const int h    = lane >> 5;

    // ---- phase A: full-row load + ballot-prefix index compaction ----
    const float4* __restrict__ Arow = (const float4*)(A + (size_t)i * N);
    float4 av[16];
    #pragma unroll
    for (int c = 0; c < 16; ++c) av[c] = Arow[c * 64 + lane];

    const float2 s = Sp[i * NH + h];   // hoisted: latency hides under ballot loop

    const unsigned long long lt = (1ull << lane) - 1ull;  // lanemask_lt
    int cnt = 0;               // wave-uniform (popcount of ballots)
    #pragma unroll
    for (int c = 0; c < 16; ++c) {
        #pragma unroll
        for (int cc = 0; cc < 4; ++cc) {
            const float vv = (cc == 0) ? av[c].x : (cc == 1) ? av[c].y
                           : (cc == 2) ? av[c].z : av[c].w;
            const unsigned long long mk = __ballot(vv != 0.f);
            if (vv != 0.f) {
                const int pos = cnt + __popcll(mk & lt);
                if (pos < 128) s_idx[wv][pos] = c * 256 + 4 * lane + cc;
            }
            cnt += __popcll(mk);
        }
    }
    if (cnt > 128) cnt = 128;                 // unreachable for this data; safety
    if (lane < 3) s_idx[wv][cnt + lane] = i;  // pad to mult-of-4 with self (masked)
    __syncthreads();            // make scattered stores visible wave-wide

    const int* __restrict__ idx = s_idx[wv];
    const int4* __restrict__ idx4 = (const int4*)idx;

    // ---- phase B: 4-wide group-pipelined weighted gather ----
    float l1 = 0.f, l2 = 0.f;
    float a1r = 0.f, a1i = 0.f, a2r = 0.f, a2i = 0.f;
    const int ng = (cnt + 3) >> 2;            // >= 1 (self loop)

    int4 ia = idx4[0];                        // group 0 indices (pads make it valid)
    int4 ib = idx4[1];                        // group 1 indices (consumed only if ng>1)
    float2 n0 = Np[ia.x * NH + h], n1 = Np[ia.y * NH + h];
    float2 n2 = Np[ia.z * NH + h], n3 = Np[ia.w * NH + h];
    float2 x0 = Xp[(size_t)ia.x * (NH * U) + lane];
    float2 x1 = Xp[(size_t)ia.y * (NH * U) + lane];
    float2 x2 = Xp[(size_t)ia.z * (NH * U) + lane];
    float2 x3 = Xp[(size_t)ia.w * (NH * U) + lane];

    #pragma unroll 1
    for (int g = 0; g < ng; ++g) {
        const float2 c0 = n0, c1 = n1, c2 = n2, c3 = n3;
        const float2 z0 = x0, z1 = x1, z2 = x2, z3 = x3;
        const int jb = g * 4;
        if (g + 1 < ng) {                     // issue group g+1 before consuming g
            n0 = Np[ib.x * NH + h]; n1 = Np[ib.y * NH + h];
            n2 = Np[ib.z * NH + h]; n3 = Np[ib.w * NH + h];
            x0 = Xp[(size_t)ib.x * (NH * U) + lane];
            x1 = Xp[(size_t)ib.y * (NH * U) + lane];
            x2 = Xp[(size_t)ib.z * (NH * U) + lane];
            x3 = Xp[(size_t)ib.w * (NH * U) + lane];
            ib = idx4[(g + 2 < ng) ? (g + 2) : (g + 1)];  // idx one group ahead
        }
        nb_acc(jb + 0 < cnt, s, c0, z0, l1, l2, a1r, a1i, a2r, a2i);
        nb_acc(jb + 1 < cnt, s, c1, z1, l1, l2, a1r, a1i, a2r, a2i);
        nb_acc(jb + 2 < cnt, s, c2, z2, l1, l2, a1r, a1i, a2r, a2i);
        nb_acc(jb + 3 < cnt, s, c3, z3, l1, l2, a1r, a1i, a2r, a2i);
    }

    const float r1 = 1.f / l1, r2 = 1.f / l2;
    // out_r [N, NH*U] then out_i [N, NH*U]; lane == h*U+u -> 256 B coalesced
    out[(size_t)i * (NH * U) + lane]                      = a1r * r1 - a2i * r2;
    out[(size_t)N * NH * U + (size_t)i * (NH * U) + lane] = a1i * r1 + a2r * r2;
}
} // anonymous namespace

extern "C" void kernel_launch(void* const* d_in, const int* in_sizes, int n_in,
                              void* d_out, int out_size, void* d_ws, size_t ws_size,
                              hipStream_t stream) {
    (void)in_sizes; (void)n_in; (void)out_size; (void)ws_size;
    const float* Hr = (const float*)d_in[0];
    const float* Hi = (const float*)d_in[1];
    const float* A  = (const float*)d_in[2];
    const float* W  = (const float*)d_in[3];
    const float* a1 = (const float*)d_in[4];
    const float* a2 = (const float*)d_in[5];
    float* out = (float*)d_out;

    float2* ws = (float2*)d_ws;          // ~2.2 MB used; fully rewritten each call
    float2* Xp = ws;                     // N*NH*U float2, interleaved [n][h][u]
    float2* Sp = Xp + (size_t)N * NH * U;// N*NH float2, [n][h]
    float2* Np = Sp + (size_t)N * NH;    // N*NH float2, [n][h]

    proj_kernel<<<N / 8, 256, 0, stream>>>(Hr, Hi, W, a1, a2, Xp, Sp, Np);
    attn_kernel<<<N / 4, 256, 0, stream>>>(A, Xp, Sp, Np, out);
}

// Round 2
// 110.388 us; speedup vs baseline: 1.0672x; 1.0142x over previous
//
#include <hip/hip_runtime.h>
#include <math.h>

namespace {
constexpr int N  = 4096;
constexpr int F  = 32;
constexpr int U  = 32;
constexpr int NH = 2;

__device__ __forceinline__ float leaky(float x) {
    return x >= 0.f ? x : 0.2f * x;
}

// X = H @ W per head (real & imag), plus attention-logit vectors.
// Interleaved layouts for single-segment gathers in attn:
//   Xp[(n*NH + h)*U + u] = (xr, xi)   -> one neighbor = 64 consecutive float2 (512 B)
//   Sp[n*NH + h] = (sr, si); Np[n*NH + h] = (nr, ni)
__global__ __launch_bounds__(256) void proj_kernel(
    const float* __restrict__ Hr, const float* __restrict__ Hi,
    const float* __restrict__ W,  const float* __restrict__ a1,
    const float* __restrict__ a2,
    float2* __restrict__ Xp, float2* __restrict__ Sp, float2* __restrict__ Np)
{
    __shared__ float sW[NH * F * U];   // 8 KB
    __shared__ float sH[2][8][F];      // 2 KB
    const int t = threadIdx.x;
    {   // vectorized W stage: 2048 floats = 512 float4, 2 per thread
        const float4* __restrict__ W4 = (const float4*)W;
        float4* __restrict__ sW4 = (float4*)sW;
        sW4[t]       = W4[t];
        sW4[t + 256] = W4[t + 256];
    }
    const int row0 = blockIdx.x * 8;
    {
        const int r = t >> 5, f = t & 31;   // 256 threads = 8 rows x 32 f
        sH[0][r][f] = Hr[(row0 + r) * F + f];
        sH[1][r][f] = Hi[(row0 + r) * F + f];
    }
    __syncthreads();

    const int r = t >> 5, u = t & 31;
    const int n = row0 + r;
    float xr[NH] = {0.f, 0.f}, xi[NH] = {0.f, 0.f};
    #pragma unroll
    for (int h = 0; h < NH; ++h) {
        #pragma unroll
        for (int f = 0; f < F; ++f) {
            const float w = sW[h * F * U + f * U + u];   // u-consecutive: conflict-free
            xr[h] += sH[0][r][f] * w;                    // broadcast read
            xi[h] += sH[1][r][f] * w;
        }
    }
    #pragma unroll
    for (int h = 0; h < NH; ++h)
        Xp[((size_t)n * NH + h) * U + u] = make_float2(xr[h], xi[h]);

    #pragma unroll
    for (int h = 0; h < NH; ++h) {
        const float av1 = a1[h * U + u], av2 = a2[h * U + u];
        float vsr = xr[h] * av1, vnr = xr[h] * av2;
        float vsi = xi[h] * av1, vni = xi[h] * av2;
        #pragma unroll
        for (int m = 16; m; m >>= 1) {   // width-32 butterfly over u
            vsr += __shfl_xor(vsr, m, 32);
            vnr += __shfl_xor(vnr, m, 32);
            vsi += __shfl_xor(vsi, m, 32);
            vni += __shfl_xor(vni, m, 32);
        }
        if (u == 0) {
            Sp[n * NH + h] = make_float2(vsr, vsi);
            Np[n * NH + h] = make_float2(vnr, vni);
        }
    }
}

__device__ __forceinline__ void nb_acc(bool valid, float2 sv, float2 nnc, float2 xc,
                                       float& l1, float& l2,
                                       float& a1r, float& a1i,
                                       float& a2r, float& a2i)
{
    float w1 = __expf(leaky(sv.x + nnc.x));   // alpha1 numerator
    float w2 = __expf(leaky(sv.y + nnc.y));   // alpha2 numerator
    w1 = valid ? w1 : 0.f;                    // padded tail contributes exactly 0
    w2 = valid ? w2 : 0.f;
    l1 += w1; l2 += w2;
    a1r += w1 * xc.x; a1i += w1 * xc.y;
    a2r += w2 * xc.x; a2i += w2 * xc.y;
}

// FOUR waves per row (one block per row):
//   wave wv scans A-row columns [wv*1024, wv*1024+1024) = 4 KB (4 dwordx4/lane,
//   all in flight), ballot-prefix-compacts its ~5-neighbor quarter list
//   (16 serial ballot steps vs 64 before), runs the 4-wide pipelined gather,
//   then waves 1-3 write 6 partial sums to LDS and wave 0 combines (softmax
//   sums are order-free, so cross-wave partial combination is exact).
// vs previous: waves 4096 -> 16384 (grid limit 16 -> 32 waves/CU), per-wave
//   serial chains /4, VGPR down ~40 (row buffer av[16] -> av[4]).
__global__ __launch_bounds__(256, 4) void attn_kernel(
    const float* __restrict__ A,
    const float2* __restrict__ Xp, const float2* __restrict__ Sp,
    const float2* __restrict__ Np,
    float* __restrict__ out)
{
    __shared__ int s_idx[4][72];          // per-wave quarter index list (16B-aligned rows)
    __shared__ float2 s_part[3][64][3];   // waves 1..3 partials

    const int wv   = threadIdx.x >> 6;    // quarter index
    const int lane = threadIdx.x & 63;
    const int i    = blockIdx.x;
    const int h    = lane >> 5;

    // ---- phase A: quarter-row load + ballot-prefix index compaction ----
    const float4* __restrict__ Arow =
        (const float4*)(A + (size_t)i * N + wv * 1024);
    float4 av[4];
    #pragma unroll
    for (int c = 0; c < 4; ++c) av[c] = Arow[c * 64 + lane];

    const float2 s = Sp[i * NH + h];      // hoisted under the scan latency

    const unsigned long long lt = (1ull << lane) - 1ull;  // lanemask_lt
    int cnt = 0;                          // wave-uniform
    #pragma unroll
    for (int c = 0; c < 4; ++c) {
        #pragma unroll
        for (int cc = 0; cc < 4; ++cc) {
            const float vv = (cc == 0) ? av[c].x : (cc == 1) ? av[c].y
                           : (cc == 2) ? av[c].z : av[c].w;
            const unsigned long long mk = __ballot(vv != 0.f);
            if (vv != 0.f) {
                const int pos = cnt + __popcll(mk & lt);
                if (pos < 64) s_idx[wv][pos] = wv * 1024 + c * 256 + 4 * lane + cc;
            }
            cnt += __popcll(mk);
        }
    }
    if (cnt > 64) cnt = 64;                   // unreachable for this data; safety
    if (lane < 4) s_idx[wv][cnt + lane] = i;  // pads: valid addr, zero weight
    __syncthreads();

    const int* __restrict__ idx = s_idx[wv];
    const int4* __restrict__ idx4 = (const int4*)idx;

    // ---- phase B: 4-wide group-pipelined weighted gather ----
    float l1 = 0.f, l2 = 0.f;
    float a1r = 0.f, a1i = 0.f, a2r = 0.f, a2i = 0.f;
    const int ng = (cnt + 3) >> 2;            // may be 0 (empty quarter)

    int4 ia = idx4[0];                        // pads make group 0 valid addrs
    int4 ib = idx4[1];                        // used only under g+1<ng guard
    float2 n0 = Np[ia.x * NH + h], n1 = Np[ia.y * NH + h];
    float2 n2 = Np[ia.z * NH + h], n3 = Np[ia.w * NH + h];
    float2 x0 = Xp[(size_t)ia.x * (NH * U) + lane];
    float2 x1 = Xp[(size_t)ia.y * (NH * U) + lane];
    float2 x2 = Xp[(size_t)ia.z * (NH * U) + lane];
    float2 x3 = Xp[(size_t)ia.w * (NH * U) + lane];

    #pragma unroll 1
    for (int g = 0; g < ng; ++g) {
        const float2 c0 = n0, c1 = n1, c2 = n2, c3 = n3;
        const float2 z0 = x0, z1 = x1, z2 = x2, z3 = x3;
        const int jb = g * 4;
        if (g + 1 < ng) {                     // issue group g+1 before consuming g
            n0 = Np[ib.x * NH + h]; n1 = Np[ib.y * NH + h];
            n2 = Np[ib.z * NH + h]; n3 = Np[ib.w * NH + h];
            x0 = Xp[(size_t)ib.x * (NH * U) + lane];
            x1 = Xp[(size_t)ib.y * (NH * U) + lane];
            x2 = Xp[(size_t)ib.z * (NH * U) + lane];
            x3 = Xp[(size_t)ib.w * (NH * U) + lane];
            ib = idx4[(g + 2 < ng) ? (g + 2) : (g + 1)];
        }
        nb_acc(jb + 0 < cnt, s, c0, z0, l1, l2, a1r, a1i, a2r, a2i);
        nb_acc(jb + 1 < cnt, s, c1, z1, l1, l2, a1r, a1i, a2r, a2i);
        nb_acc(jb + 2 < cnt, s, c2, z2, l1, l2, a1r, a1i, a2r, a2i);
        nb_acc(jb + 3 < cnt, s, c3, z3, l1, l2, a1r, a1i, a2r, a2i);
    }

    // ---- cross-wave combine (exact: plain-exp sums are order-free) ----
    if (wv > 0) {
        s_part[wv - 1][lane][0] = make_float2(l1, l2);
        s_part[wv - 1][lane][1] = make_float2(a1r, a1i);
        s_part[wv - 1][lane][2] = make_float2(a2r, a2i);
    }
    __syncthreads();
    if (wv == 0) {
        #pragma unroll
        for (int p = 0; p < 3; ++p) {
            const float2 pl = s_part[p][lane][0];
            const float2 p1 = s_part[p][lane][1];
            const float2 p2 = s_part[p][lane][2];
            l1  += pl.x; l2  += pl.y;
            a1r += p1.x; a1i += p1.y;
            a2r += p2.x; a2i += p2.y;
        }
        const float r1 = 1.f / l1, r2 = 1.f / l2;
        // out_r [N, NH*U] then out_i [N, NH*U]; lane == h*U+u -> 256 B coalesced
        out[(size_t)i * (NH * U) + lane]                      = a1r * r1 - a2i * r2;
        out[(size_t)N * NH * U + (size_t)i * (NH * U) + lane] = a1i * r1 + a2r * r2;
    }
}
} // anonymous namespace

extern "C" void kernel_launch(void* const* d_in, const int* in_sizes, int n_in,
                              void* d_out, int out_size, void* d_ws, size_t ws_size,
                              hipStream_t stream) {
    (void)in_sizes; (void)n_in; (void)out_size; (void)ws_size;
    const float* Hr = (const float*)d_in[0];
    const float* Hi = (const float*)d_in[1];
    const float* A  = (const float*)d_in[2];
    const float* W  = (const float*)d_in[3];
    const float* a1 = (const float*)d_in[4];
    const float* a2 = (const float*)d_in[5];
    float* out = (float*)d_out;

    float2* ws = (float2*)d_ws;          // ~2.2 MB used; fully rewritten each call
    float2* Xp = ws;                     // N*NH*U float2, interleaved [n][h][u]
    float2* Sp = Xp + (size_t)N * NH * U;// N*NH float2, [n][h]
    float2* Np = Sp + (size_t)N * NH;    // N*NH float2, [n][h]

    proj_kernel<<<N / 8, 256, 0, stream>>>(Hr, Hi, W, a1, a2, Xp, Sp, Np);
    attn_kernel<<<N, 256, 0, stream>>>(A, Xp, Sp, Np, out);
}